// Round 2
// baseline (969.329 us; speedup 1.0000x reference)
//
#include <hip/hip_runtime.h>
#include <math.h>

#define NN 50000
#define NE 400000
#define FDIM 128

constexpr float INV_SCALE = 0.17677669529663687f; // 1/sqrt(32)
constexpr float LN_EPS = 1e-5f;

typedef short bf16x8 __attribute__((ext_vector_type(8)));
typedef float f32x4 __attribute__((ext_vector_type(4)));

static __device__ __forceinline__ short f2bf(float f) {
    unsigned u = __builtin_bit_cast(unsigned, f);
    u += 0x7FFFu + ((u >> 16) & 1u);   // RNE
    return (short)(u >> 16);
}
static __device__ __forceinline__ float bf2f(short h) {
    unsigned u = ((unsigned)(unsigned short)h) << 16;
    return __builtin_bit_cast(float, u);
}

// Load the 4 K-step A fragments for this wave's 16-row stripe from swizzled LDS.
static __device__ __forceinline__ void load_afrags(const short* At, int w, int l, bf16x8* a) {
    int lr = l & 15, lq = l >> 4;
    int arow = w * 16 + lr;
#pragma unroll
    for (int ks = 0; ks < 4; ++ks) {
        int ch = ks * 4 + lq;
        a[ks] = *(const bf16x8*)(At + arow * FDIM + ((ch ^ (arow & 7)) * 8));
    }
}

// OUT(16x128 per wave) = A(16x128) @ W^T + bias, W row-major [128][128] bf16.
static __device__ __forceinline__ void mfma_gemm(const bf16x8* a,
                                                 const short* __restrict__ W,
                                                 const float* __restrict__ bias,
                                                 int lr, int lq, f32x4* acc) {
#pragma unroll
    for (int n = 0; n < 8; ++n) {
        float bb = bias[n * 16 + lr];
        f32x4 t; t[0] = bb; t[1] = bb; t[2] = bb; t[3] = bb;
        acc[n] = t;
#pragma unroll
        for (int ks = 0; ks < 4; ++ks) {
            bf16x8 b = *(const bf16x8*)(W + (n * 16 + lr) * FDIM + ks * 32 + lq * 8);
            acc[n] = __builtin_amdgcn_mfma_f32_16x16x32_bf16(a[ks], b, acc[n], 0, 0, 0);
        }
    }
}

__global__ __launch_bounds__(256) void convert_weights(
    const float* __restrict__ w0, const float* __restrict__ w1,
    const float* __restrict__ w2, const float* __restrict__ w3,
    const float* __restrict__ w4, const float* __restrict__ w5,
    short* __restrict__ out) {
    int idx = blockIdx.x * 256 + threadIdx.x;   // 6*16384 total
    const float* srcs[6] = {w0, w1, w2, w3, w4, w5};
    out[idx] = f2bf(srcs[idx >> 14][idx & 16383]);
}

// ---- counting sort by dst ----
__global__ __launch_bounds__(256) void hist_kernel(const int* __restrict__ dst,
                                                   int* __restrict__ hist) {
    int e = blockIdx.x * 256 + threadIdx.x;
    if (e < NE) atomicAdd(&hist[dst[e]], 1);
}

__global__ __launch_bounds__(256) void scan_kernel(const int* __restrict__ hist,
                                                   int* __restrict__ cursor) {
    __shared__ int wsum[4];
    __shared__ int srun;
    int tid = threadIdx.x;
    int lane = tid & 63, w = tid >> 6;
    if (tid == 0) srun = 0;
    __syncthreads();
    for (int base = 0; base < NN; base += 256) {
        int i = base + tid;
        int v = (i < NN) ? hist[i] : 0;
        int inc = v;
#pragma unroll
        for (int off = 1; off < 64; off <<= 1) {
            int t = __shfl_up(inc, off);
            if (lane >= off) inc += t;
        }
        if (lane == 63) wsum[w] = inc;
        __syncthreads();
        int wo = 0;
        for (int j = 0; j < w; ++j) wo += wsum[j];
        int run = srun;
        if (i < NN) cursor[i] = run + wo + inc - v;   // exclusive
        __syncthreads();
        if (tid == 255) srun = run + wo + inc;
        __syncthreads();
    }
}

__global__ __launch_bounds__(256) void scatter_kernel(const int* __restrict__ dst,
                                                      int* __restrict__ cursor,
                                                      int* __restrict__ sidx) {
    int e = blockIdx.x * 256 + threadIdx.x;
    if (e < NE) sidx[atomicAdd(&cursor[dst[e]], 1)] = e;
}

// ---- node projections: q,k,v (bf16) + xout = nf@Wout^T+bout (f32) ----
__global__ __launch_bounds__(256) void node_proj_kernel(
    const float* __restrict__ nf,
    const short* __restrict__ wq16, const short* __restrict__ wk16,
    const short* __restrict__ wv16, const short* __restrict__ wo16,
    const float* __restrict__ bq, const float* __restrict__ bk,
    const float* __restrict__ bv, const float* __restrict__ bo,
    short* __restrict__ q, short* __restrict__ k, short* __restrict__ v,
    float* __restrict__ xout) {
    __shared__ __align__(16) short At[64 * FDIM];
    int m0  = blockIdx.x * 64;
    int tid = threadIdx.x;
#pragma unroll
    for (int j = 0; j < 4; ++j) {
        int row = (tid >> 4) + j * 16;
        int g   = tid & 15;
        int m   = m0 + row;
        float4 a0 = make_float4(0.f, 0.f, 0.f, 0.f);
        float4 a1 = make_float4(0.f, 0.f, 0.f, 0.f);
        if (m < NN) {
            const float4* p = (const float4*)(nf + (size_t)m * FDIM + g * 8);
            a0 = p[0]; a1 = p[1];
        }
        bf16x8 h;
        h[0] = f2bf(a0.x); h[1] = f2bf(a0.y); h[2] = f2bf(a0.z); h[3] = f2bf(a0.w);
        h[4] = f2bf(a1.x); h[5] = f2bf(a1.y); h[6] = f2bf(a1.z); h[7] = f2bf(a1.w);
        *(bf16x8*)(At + row * FDIM + ((g ^ (row & 7)) * 8)) = h;
    }
    __syncthreads();
    int w = tid >> 6, l = tid & 63;
    int lr = l & 15, lq = l >> 4;
    bf16x8 a[4];
    load_afrags(At, w, l, a);
    f32x4 acc[8];
    const short* Ws[3] = {wq16, wk16, wv16};
    const float* Bs[3] = {bq, bk, bv};
    short*       Os[3] = {q, k, v};
#pragma unroll
    for (int t = 0; t < 3; ++t) {
        mfma_gemm(a, Ws[t], Bs[t], lr, lq, acc);
#pragma unroll
        for (int n = 0; n < 8; ++n)
#pragma unroll
            for (int r = 0; r < 4; ++r) {
                int m = m0 + w * 16 + lq * 4 + r;
                if (m < NN) Os[t][(size_t)m * FDIM + n * 16 + lr] = f2bf(acc[n][r]);
            }
    }
    mfma_gemm(a, wo16, bo, lr, lq, acc);
#pragma unroll
    for (int n = 0; n < 8; ++n)
#pragma unroll
        for (int r = 0; r < 4; ++r) {
            int m = m0 + w * 16 + lq * 4 + r;
            if (m < NN) xout[(size_t)m * FDIM + n * 16 + lr] = acc[n][r];
        }
}

// ---- fused edge kernel over dst-sorted edges ----
__global__ __launch_bounds__(256) void edge_kernel(
    const float* __restrict__ ef, const int* __restrict__ src, const int* __restrict__ dst,
    const int* __restrict__ sidx,
    const short* __restrict__ we16, const short* __restrict__ wev16,
    const float* __restrict__ be, const float* __restrict__ bev,
    const short* __restrict__ qbf, const short* __restrict__ kbf, const short* __restrict__ vbf,
    const float* __restrict__ ln_eg, const float* __restrict__ ln_eb,
    float* __restrict__ agg, float* __restrict__ yout) {
    __shared__ __align__(16) short At[64 * FDIM];   // ef tile (bf16, swizzled); later attn (bf16, linear)
    __shared__ __align__(16) float sc[64 * 4];
    __shared__ int oL[64], sL[64], dL[64];
    int e0  = blockIdx.x * 64;
    int tid = threadIdx.x;

    // stage gathered ef rows into LDS (bf16, 16B-chunk XOR swizzle)
#pragma unroll
    for (int j = 0; j < 4; ++j) {
        int row = (tid >> 4) + j * 16;
        int g   = tid & 15;
        int o   = sidx[e0 + row];
        const float4* p = (const float4*)(ef + (size_t)o * FDIM + g * 8);
        float4 a0 = p[0], a1 = p[1];
        bf16x8 h;
        h[0] = f2bf(a0.x); h[1] = f2bf(a0.y); h[2] = f2bf(a0.z); h[3] = f2bf(a0.w);
        h[4] = f2bf(a1.x); h[5] = f2bf(a1.y); h[6] = f2bf(a1.z); h[7] = f2bf(a1.w);
        *(bf16x8*)(At + row * FDIM + ((g ^ (row & 7)) * 8)) = h;
    }

    int w = tid >> 6, l = tid & 63;
    {   // scores: lane = one (edge-in-tile, head); also fill oL/sL/dL
        int eidx = w * 16 + (l >> 2);
        int h    = l & 3;
        int o    = sidx[e0 + eidx];
        int se = src[o], de = dst[o];
        if (h == 0) { oL[eidx] = o; sL[eidx] = se; dL[eidx] = de; }
        const bf16x8* qp = (const bf16x8*)(qbf + (size_t)se * FDIM + h * 32);
        const bf16x8* kp = (const bf16x8*)(kbf + (size_t)de * FDIM + h * 32);
        float s = 0.f;
#pragma unroll
        for (int i = 0; i < 4; ++i) {
            bf16x8 qa = qp[i], ka = kp[i];
#pragma unroll
            for (int jj = 0; jj < 8; ++jj) s += bf2f(qa[jj]) * bf2f(ka[jj]);
        }
        sc[eidx * 4 + h] = s * INV_SCALE;
    }
    __syncthreads();

    int lr = l & 15, lq = l >> 4;
    bf16x8 a[4];
    load_afrags(At, w, l, a);
    __syncthreads();   // everyone done reading At before attn overwrites it

    f32x4 me[8], mvv[8];
    mfma_gemm(a, we16, be, lr, lq, me);
    mfma_gemm(a, wev16, bev, lr, lq, mvv);

    int rowb = w * 16 + lq * 4;
    float sr[4][4];
#pragma unroll
    for (int r = 0; r < 4; ++r) {
        f32x4 t = *(const f32x4*)(sc + (rowb + r) * 4);
        sr[r][0] = t[0]; sr[r][1] = t[1]; sr[r][2] = t[2]; sr[r][3] = t[3];
    }
#pragma unroll
    for (int n = 0; n < 8; ++n)
#pragma unroll
        for (int r = 0; r < 4; ++r)
            me[n][r] += sr[r][n >> 1];

    // softmax over heads; store attn (bf16) into At alias, linear [row][col]
    short* attnL = At;
#pragma unroll
    for (int r = 0; r < 4; ++r) {
#pragma unroll
        for (int half = 0; half < 2; ++half) {
            float v0 = me[half][r],     v1 = me[half + 2][r];
            float v2 = me[half + 4][r], v3 = me[half + 6][r];
            float mx = fmaxf(fmaxf(v0, v1), fmaxf(v2, v3));
            float x0 = __expf(v0 - mx), x1 = __expf(v1 - mx);
            float x2 = __expf(v2 - mx), x3 = __expf(v3 - mx);
            float inv = 1.f / (x0 + x1 + x2 + x3);
            float at[4] = {x0 * inv, x1 * inv, x2 * inv, x3 * inv};
#pragma unroll
            for (int h = 0; h < 4; ++h)
                attnL[(rowb + r) * FDIM + (2 * h + half) * 16 + lr] = f2bf(at[h]);
        }
    }

    // y = silu(layernorm(m)) + (edge@Wev^T + bev), scattered to original edge row
#pragma unroll
    for (int r = 0; r < 4; ++r) {
        float sum1 = 0.f, sum2 = 0.f;
#pragma unroll
        for (int n = 0; n < 8; ++n) { float t = me[n][r]; sum1 += t; sum2 += t * t; }
#pragma unroll
        for (int off = 1; off < 16; off <<= 1) {
            sum1 += __shfl_xor(sum1, off);
            sum2 += __shfl_xor(sum2, off);
        }
        float mean = sum1 * (1.f / 128.f);
        float var  = sum2 * (1.f / 128.f) - mean * mean;
        float rstd = rsqrtf(var + LN_EPS);
        int orow = oL[rowb + r];
#pragma unroll
        for (int n = 0; n < 8; ++n) {
            int col = n * 16 + lr;
            float t  = (me[n][r] - mean) * rstd * ln_eg[col] + ln_eb[col];
            float si = t / (1.f + __expf(-t));
            yout[(size_t)orow * FDIM + col] = si + mvv[n][r];
        }
    }
    __syncthreads();   // attn fully in LDS

    // column-parallel aggregation over sorted-dst runs: few coalesced atomics
    {
        int c  = tid & 127;
        int hh = tid >> 7;          // 0: edges 0..31, 1: edges 32..63
        int j0 = hh * 32, j1 = j0 + 32;
        float acc = 0.f;
        int cur = dL[j0];
        for (int j = j0; j < j1; ++j) {
            int d = dL[j];
            if (d != cur) {
                unsafeAtomicAdd(&agg[(size_t)cur * FDIM + c], acc);
                acc = 0.f; cur = d;
            }
            float vv = bf2f(vbf[(size_t)sL[j] * FDIM + c]);
            float aa = bf2f(attnL[j * FDIM + c]);
            acc += vv * aa;
        }
        unsafeAtomicAdd(&agg[(size_t)cur * FDIM + c], acc);
    }
}

__global__ __launch_bounds__(256) void node_epilogue(
    const float* __restrict__ agg,
    const float* __restrict__ ln_ng, const float* __restrict__ ln_nb,
    float* __restrict__ xout) {
    int row = blockIdx.x * 4 + (threadIdx.x >> 6);
    if (row >= NN) return;
    int l = threadIdx.x & 63;
    float2 aa = *(const float2*)(agg + (size_t)row * FDIM + l * 2);
    float sum1 = aa.x + aa.y, sum2 = aa.x * aa.x + aa.y * aa.y;
#pragma unroll
    for (int off = 1; off < 64; off <<= 1) {
        sum1 += __shfl_xor(sum1, off);
        sum2 += __shfl_xor(sum2, off);
    }
    float mean = sum1 * (1.f / 128.f);
    float var  = sum2 * (1.f / 128.f) - mean * mean;
    float rstd = rsqrtf(var + LN_EPS);
    float2 gg = *(const float2*)(ln_ng + l * 2);
    float2 bb = *(const float2*)(ln_nb + l * 2);
    float t0 = (aa.x - mean) * rstd * gg.x + bb.x;
    float t1 = (aa.y - mean) * rstd * gg.y + bb.y;
    float s0 = t0 / (1.f + __expf(-t0));
    float s1 = t1 / (1.f + __expf(-t1));
    float2 o = *(const float2*)(xout + (size_t)row * FDIM + l * 2);
    o.x += s0;
    o.y += s1;
    *(float2*)(xout + (size_t)row * FDIM + l * 2) = o;
}

extern "C" void kernel_launch(void* const* d_in, const int* in_sizes, int n_in,
                              void* d_out, int out_size, void* d_ws, size_t ws_size,
                              hipStream_t stream) {
    const float* nf   = (const float*)d_in[0];
    const float* ef   = (const float*)d_in[1];
    const int*   src  = (const int*)d_in[2];
    const int*   dst  = (const int*)d_in[3];
    const float* Wq   = (const float*)d_in[4];  const float* bq   = (const float*)d_in[5];
    const float* Wk   = (const float*)d_in[6];  const float* bk   = (const float*)d_in[7];
    const float* Wv   = (const float*)d_in[8];  const float* bv   = (const float*)d_in[9];
    const float* We   = (const float*)d_in[10]; const float* be   = (const float*)d_in[11];
    const float* Wev  = (const float*)d_in[12]; const float* bev  = (const float*)d_in[13];
    const float* Wout = (const float*)d_in[14]; const float* bout = (const float*)d_in[15];
    const float* ln_ng = (const float*)d_in[16]; const float* ln_nb = (const float*)d_in[17];
    const float* ln_eg = (const float*)d_in[18]; const float* ln_eb = (const float*)d_in[19];

    float* xout = (float*)d_out;              // [N*128]
    float* yout = xout + (size_t)NN * FDIM;   // [E*128]

    char* ws = (char*)d_ws;
    short* qbf  = (short*)ws;                                   ws += (size_t)NN * FDIM * 2;
    short* kbf  = (short*)ws;                                   ws += (size_t)NN * FDIM * 2;
    short* vbf  = (short*)ws;                                   ws += (size_t)NN * FDIM * 2;
    float* agg  = (float*)ws;                                   ws += (size_t)NN * FDIM * 4;
    short* w16  = (short*)ws;                                   ws += (size_t)6 * 16384 * 2;
    int*   hist = (int*)ws;                                     ws += (size_t)NN * 4;
    int*   curs = (int*)ws;                                     ws += (size_t)NN * 4;
    int*   sidx = (int*)ws;                                     ws += (size_t)NE * 4;
    short* wq16  = w16;
    short* wk16  = w16 + 16384;
    short* wv16  = w16 + 32768;
    short* we16  = w16 + 49152;
    short* wev16 = w16 + 65536;
    short* wo16  = w16 + 81920;

    hipMemsetAsync(agg, 0, (size_t)NN * FDIM * sizeof(float), stream);
    hipMemsetAsync(hist, 0, (size_t)NN * sizeof(int), stream);
    convert_weights<<<384, 256, 0, stream>>>(Wq, Wk, Wv, We, Wev, Wout, w16);
    hist_kernel<<<(NE + 255) / 256, 256, 0, stream>>>(dst, hist);
    scan_kernel<<<1, 256, 0, stream>>>(hist, curs);
    scatter_kernel<<<(NE + 255) / 256, 256, 0, stream>>>(dst, curs, sidx);
    node_proj_kernel<<<(NN + 63) / 64, 256, 0, stream>>>(
        nf, wq16, wk16, wv16, wo16, bq, bk, bv, bout, qbf, kbf, vbf, xout);
    edge_kernel<<<NE / 64, 256, 0, stream>>>(
        ef, src, dst, sidx, we16, wev16, be, bev, qbf, kbf, vbf, ln_eg, ln_eb, agg, yout);
    node_epilogue<<<(NN + 3) / 4, 256, 0, stream>>>(agg, ln_ng, ln_nb, xout);
}

// Round 3
// 856.173 us; speedup vs baseline: 1.1322x; 1.1322x over previous
//
#include <hip/hip_runtime.h>
#include <math.h>

#define NN 50000
#define NE 400000
#define FDIM 128
#define NB 196   // ceil(NN/256)

constexpr float INV_SCALE = 0.17677669529663687f; // 1/sqrt(32)
constexpr float LN_EPS = 1e-5f;

typedef short bf16x8 __attribute__((ext_vector_type(8)));
typedef float f32x4 __attribute__((ext_vector_type(4)));

static __device__ __forceinline__ short f2bf(float f) {
    unsigned u = __builtin_bit_cast(unsigned, f);
    u += 0x7FFFu + ((u >> 16) & 1u);   // RNE
    return (short)(u >> 16);
}
static __device__ __forceinline__ float bf2f(short h) {
    unsigned u = ((unsigned)(unsigned short)h) << 16;
    return __builtin_bit_cast(float, u);
}

// Load the 4 K-step A fragments for this wave's 16-row stripe from swizzled LDS.
static __device__ __forceinline__ void load_afrags(const short* At, int w, int l, bf16x8* a) {
    int lr = l & 15, lq = l >> 4;
    int arow = w * 16 + lr;
#pragma unroll
    for (int ks = 0; ks < 4; ++ks) {
        int ch = ks * 4 + lq;
        a[ks] = *(const bf16x8*)(At + arow * FDIM + ((ch ^ (arow & 7)) * 8));
    }
}

// OUT(16x128 per wave) = A(16x128) @ W^T + bias, W row-major [128][128] bf16.
static __device__ __forceinline__ void mfma_gemm(const bf16x8* a,
                                                 const short* __restrict__ W,
                                                 const float* __restrict__ bias,
                                                 int lr, int lq, f32x4* acc) {
#pragma unroll
    for (int n = 0; n < 8; ++n) {
        float bb = bias[n * 16 + lr];
        f32x4 t; t[0] = bb; t[1] = bb; t[2] = bb; t[3] = bb;
        acc[n] = t;
#pragma unroll
        for (int ks = 0; ks < 4; ++ks) {
            bf16x8 b = *(const bf16x8*)(W + (n * 16 + lr) * FDIM + ks * 32 + lq * 8);
            acc[n] = __builtin_amdgcn_mfma_f32_16x16x32_bf16(a[ks], b, acc[n], 0, 0, 0);
        }
    }
}

__global__ __launch_bounds__(256) void convert_weights(
    const float* __restrict__ w0, const float* __restrict__ w1,
    const float* __restrict__ w2, const float* __restrict__ w3,
    const float* __restrict__ w4, const float* __restrict__ w5,
    short* __restrict__ out) {
    int idx = blockIdx.x * 256 + threadIdx.x;   // 6*16384 total
    const float* srcs[6] = {w0, w1, w2, w3, w4, w5};
    out[idx] = f2bf(srcs[idx >> 14][idx & 16383]);
}

// ---- CSR build: hist -> 3-phase exclusive scan -> scatter ----
__global__ __launch_bounds__(256) void hist_kernel(const int* __restrict__ dst,
                                                   int* __restrict__ hist) {
    int e = blockIdx.x * 256 + threadIdx.x;
    if (e < NE) atomicAdd(&hist[dst[e]], 1);
}

__global__ __launch_bounds__(256) void scanA_kernel(const int* __restrict__ hist,
                                                    int* __restrict__ row_start,
                                                    int* __restrict__ bsum) {
    __shared__ int wsum[4];
    int tid = threadIdx.x, lane = tid & 63, w = tid >> 6;
    int i = blockIdx.x * 256 + tid;
    int v = (i < NN) ? hist[i] : 0;
    int inc = v;
#pragma unroll
    for (int off = 1; off < 64; off <<= 1) {
        int t = __shfl_up(inc, off);
        if (lane >= off) inc += t;
    }
    if (lane == 63) wsum[w] = inc;
    __syncthreads();
    int wo = 0;
    for (int j = 0; j < w; ++j) wo += wsum[j];
    if (i < NN) row_start[i] = wo + inc - v;
    if (tid == 255) bsum[blockIdx.x] = wo + inc;
}

__global__ __launch_bounds__(256) void scanB_kernel(int* __restrict__ bsum) {
    __shared__ int wsum[4];
    int tid = threadIdx.x, lane = tid & 63, w = tid >> 6;
    int v = (tid < NB) ? bsum[tid] : 0;
    int inc = v;
#pragma unroll
    for (int off = 1; off < 64; off <<= 1) {
        int t = __shfl_up(inc, off);
        if (lane >= off) inc += t;
    }
    if (lane == 63) wsum[w] = inc;
    __syncthreads();
    int wo = 0;
    for (int j = 0; j < w; ++j) wo += wsum[j];
    if (tid < NB) bsum[tid] = wo + inc - v;   // exclusive
}

__global__ __launch_bounds__(256) void scanC_kernel(int* __restrict__ row_start,
                                                    const int* __restrict__ bsum,
                                                    int* __restrict__ cursor) {
    int i = blockIdx.x * 256 + threadIdx.x;
    if (i < NN) {
        int s = row_start[i] + bsum[blockIdx.x];
        row_start[i] = s;
        cursor[i] = s;
    }
}

__global__ __launch_bounds__(256) void scatter_kernel(const int* __restrict__ dst,
                                                      int* __restrict__ cursor,
                                                      int* __restrict__ sidx) {
    int e = blockIdx.x * 256 + threadIdx.x;
    if (e < NE) sidx[atomicAdd(&cursor[dst[e]], 1)] = e;
}

// ---- node projections: q,k,v (bf16) + xout = nf@Wout^T+bout (f32) ----
__global__ __launch_bounds__(256) void node_proj_kernel(
    const float* __restrict__ nf,
    const short* __restrict__ wq16, const short* __restrict__ wk16,
    const short* __restrict__ wv16, const short* __restrict__ wo16,
    const float* __restrict__ bq, const float* __restrict__ bk,
    const float* __restrict__ bv, const float* __restrict__ bo,
    short* __restrict__ q, short* __restrict__ k, short* __restrict__ v,
    float* __restrict__ xout) {
    __shared__ __align__(16) short At[64 * FDIM];
    int m0  = blockIdx.x * 64;
    int tid = threadIdx.x;
#pragma unroll
    for (int j = 0; j < 4; ++j) {
        int row = (tid >> 4) + j * 16;
        int g   = tid & 15;
        int m   = m0 + row;
        float4 a0 = make_float4(0.f, 0.f, 0.f, 0.f);
        float4 a1 = make_float4(0.f, 0.f, 0.f, 0.f);
        if (m < NN) {
            const float4* p = (const float4*)(nf + (size_t)m * FDIM + g * 8);
            a0 = p[0]; a1 = p[1];
        }
        bf16x8 h;
        h[0] = f2bf(a0.x); h[1] = f2bf(a0.y); h[2] = f2bf(a0.z); h[3] = f2bf(a0.w);
        h[4] = f2bf(a1.x); h[5] = f2bf(a1.y); h[6] = f2bf(a1.z); h[7] = f2bf(a1.w);
        *(bf16x8*)(At + row * FDIM + ((g ^ (row & 7)) * 8)) = h;
    }
    __syncthreads();
    int w = tid >> 6, l = tid & 63;
    int lr = l & 15, lq = l >> 4;
    bf16x8 a[4];
    load_afrags(At, w, l, a);
    f32x4 acc[8];
    const short* Ws[3] = {wq16, wk16, wv16};
    const float* Bs[3] = {bq, bk, bv};
    short*       Os[3] = {q, k, v};
#pragma unroll
    for (int t = 0; t < 3; ++t) {
        mfma_gemm(a, Ws[t], Bs[t], lr, lq, acc);
#pragma unroll
        for (int n = 0; n < 8; ++n)
#pragma unroll
            for (int r = 0; r < 4; ++r) {
                int m = m0 + w * 16 + lq * 4 + r;
                if (m < NN) Os[t][(size_t)m * FDIM + n * 16 + lr] = f2bf(acc[n][r]);
            }
    }
    mfma_gemm(a, wo16, bo, lr, lq, acc);
#pragma unroll
    for (int n = 0; n < 8; ++n)
#pragma unroll
        for (int r = 0; r < 4; ++r) {
            int m = m0 + w * 16 + lq * 4 + r;
            if (m < NN) xout[(size_t)m * FDIM + n * 16 + lr] = acc[n][r];
        }
}

// ---- E1: natural-order edge stream: m, y, attn ----
__global__ __launch_bounds__(256) void edge_m_kernel(
    const float* __restrict__ ef, const int* __restrict__ src, const int* __restrict__ dst,
    const short* __restrict__ we16, const short* __restrict__ wev16,
    const float* __restrict__ be, const float* __restrict__ bev,
    const short* __restrict__ qbf, const short* __restrict__ kbf,
    const float* __restrict__ ln_eg, const float* __restrict__ ln_eb,
    short* __restrict__ attn, float* __restrict__ yout) {
    __shared__ __align__(16) short At[64 * FDIM];   // ef tile (swizzled); later attn (linear)
    __shared__ __align__(16) float sc[64 * 4];
    int e0  = blockIdx.x * 64;
    int tid = threadIdx.x;

    // stage ef tile (coalesced, natural order)
#pragma unroll
    for (int j = 0; j < 4; ++j) {
        int row = (tid >> 4) + j * 16;
        int g   = tid & 15;
        const float4* p = (const float4*)(ef + (size_t)(e0 + row) * FDIM + g * 8);
        float4 a0 = p[0], a1 = p[1];
        bf16x8 h;
        h[0] = f2bf(a0.x); h[1] = f2bf(a0.y); h[2] = f2bf(a0.z); h[3] = f2bf(a0.w);
        h[4] = f2bf(a1.x); h[5] = f2bf(a1.y); h[6] = f2bf(a1.z); h[7] = f2bf(a1.w);
        *(bf16x8*)(At + row * FDIM + ((g ^ (row & 7)) * 8)) = h;
    }

    int w = tid >> 6, l = tid & 63;
    {   // scores: one lane per (edge-in-tile, head)
        int eidx = w * 16 + (l >> 2);
        int h    = l & 3;
        int eg   = e0 + eidx;
        int se = src[eg], de = dst[eg];
        const bf16x8* qp = (const bf16x8*)(qbf + (size_t)se * FDIM + h * 32);
        const bf16x8* kp = (const bf16x8*)(kbf + (size_t)de * FDIM + h * 32);
        float s = 0.f;
#pragma unroll
        for (int i = 0; i < 4; ++i) {
            bf16x8 qa = qp[i], ka = kp[i];
#pragma unroll
            for (int jj = 0; jj < 8; ++jj) s += bf2f(qa[jj]) * bf2f(ka[jj]);
        }
        sc[eidx * 4 + h] = s * INV_SCALE;
    }
    __syncthreads();

    int lr = l & 15, lq = l >> 4;
    bf16x8 a[4];
    load_afrags(At, w, l, a);
    __syncthreads();   // all waves done reading At before attn overwrites it

    f32x4 me[8], mvv[8];
    mfma_gemm(a, we16, be, lr, lq, me);
    mfma_gemm(a, wev16, bev, lr, lq, mvv);

    int rowb = w * 16 + lq * 4;
#pragma unroll
    for (int r = 0; r < 4; ++r) {
        f32x4 t = *(const f32x4*)(sc + (rowb + r) * 4);
#pragma unroll
        for (int n = 0; n < 8; ++n)
            me[n][r] += ((const float*)&t)[n >> 1];
    }

    // softmax over heads -> attn (bf16) into LDS alias, linear [row][col]
    short* attnL = At;
#pragma unroll
    for (int r = 0; r < 4; ++r) {
#pragma unroll
        for (int half = 0; half < 2; ++half) {
            float v0 = me[half][r],     v1 = me[half + 2][r];
            float v2 = me[half + 4][r], v3 = me[half + 6][r];
            float mx = fmaxf(fmaxf(v0, v1), fmaxf(v2, v3));
            float x0 = __expf(v0 - mx), x1 = __expf(v1 - mx);
            float x2 = __expf(v2 - mx), x3 = __expf(v3 - mx);
            float inv = 1.f / (x0 + x1 + x2 + x3);
            float at[4] = {x0 * inv, x1 * inv, x2 * inv, x3 * inv};
#pragma unroll
            for (int h = 0; h < 4; ++h)
                attnL[(rowb + r) * FDIM + (2 * h + half) * 16 + lr] = f2bf(at[h]);
        }
    }

    // y = silu(layernorm(m)) + (ef@Wev^T + bev), coalesced write
#pragma unroll
    for (int r = 0; r < 4; ++r) {
        float sum1 = 0.f, sum2 = 0.f;
#pragma unroll
        for (int n = 0; n < 8; ++n) { float t = me[n][r]; sum1 += t; sum2 += t * t; }
#pragma unroll
        for (int off = 1; off < 16; off <<= 1) {
            sum1 += __shfl_xor(sum1, off);
            sum2 += __shfl_xor(sum2, off);
        }
        float mean = sum1 * (1.f / 128.f);
        float var  = sum2 * (1.f / 128.f) - mean * mean;
        float rstd = rsqrtf(var + LN_EPS);
        int eg = e0 + rowb + r;
#pragma unroll
        for (int n = 0; n < 8; ++n) {
            int col = n * 16 + lr;
            float t  = (me[n][r] - mean) * rstd * ln_eg[col] + ln_eb[col];
            float si = t / (1.f + __expf(-t));
            yout[(size_t)eg * FDIM + col] = si + mvv[n][r];
        }
    }
    __syncthreads();   // attn fully in LDS

    // stream attn LDS -> global, fully coalesced 16B stores
#pragma unroll
    for (int j = 0; j < 4; ++j) {
        int row = (tid >> 4) + j * 16;
        int g   = tid & 15;
        *(bf16x8*)(attn + (size_t)(e0 + row) * FDIM + g * 8) =
            *(const bf16x8*)(attnL + row * FDIM + g * 8);
    }
}

// ---- E2: per-node CSR aggregation + LN + SiLU + residual (no atomics) ----
__global__ __launch_bounds__(256) void node_agg_kernel(
    const int* __restrict__ row_start, const int* __restrict__ hist,
    const int* __restrict__ sidx, const int* __restrict__ src,
    const short* __restrict__ attn, const short* __restrict__ vbf,
    const float* __restrict__ ln_ng, const float* __restrict__ ln_nb,
    float* __restrict__ xout) {
    int tid = threadIdx.x;
    int w = tid >> 6, l = tid & 63;
    int n = blockIdx.x * 4 + w;
    if (n >= NN) return;
    int start = row_start[n];
    int deg   = hist[n];
    float a0 = 0.f, a1 = 0.f;
    for (int j = 0; j < deg; ++j) {
        int e = sidx[start + j];
        int s = src[e];
        unsigned av = *(const unsigned*)(attn + (size_t)e * FDIM + l * 2);
        unsigned vv = *(const unsigned*)(vbf  + (size_t)s * FDIM + l * 2);
        float alo = __builtin_bit_cast(float, av << 16);
        float ahi = __builtin_bit_cast(float, av & 0xFFFF0000u);
        float vlo = __builtin_bit_cast(float, vv << 16);
        float vhi = __builtin_bit_cast(float, vv & 0xFFFF0000u);
        a0 += alo * vlo;
        a1 += ahi * vhi;
    }
    float sum1 = a0 + a1, sum2 = a0 * a0 + a1 * a1;
#pragma unroll
    for (int off = 1; off < 64; off <<= 1) {
        sum1 += __shfl_xor(sum1, off);
        sum2 += __shfl_xor(sum2, off);
    }
    float mean = sum1 * (1.f / 128.f);
    float var  = sum2 * (1.f / 128.f) - mean * mean;
    float rstd = rsqrtf(var + LN_EPS);
    float2 gg = *(const float2*)(ln_ng + l * 2);
    float2 bb = *(const float2*)(ln_nb + l * 2);
    float t0 = (a0 - mean) * rstd * gg.x + bb.x;
    float t1 = (a1 - mean) * rstd * gg.y + bb.y;
    float s0 = t0 / (1.f + __expf(-t0));
    float s1 = t1 / (1.f + __expf(-t1));
    float2 o = *(const float2*)(xout + (size_t)n * FDIM + l * 2);
    o.x += s0;
    o.y += s1;
    *(float2*)(xout + (size_t)n * FDIM + l * 2) = o;
}

extern "C" void kernel_launch(void* const* d_in, const int* in_sizes, int n_in,
                              void* d_out, int out_size, void* d_ws, size_t ws_size,
                              hipStream_t stream) {
    const float* nf   = (const float*)d_in[0];
    const float* ef   = (const float*)d_in[1];
    const int*   src  = (const int*)d_in[2];
    const int*   dst  = (const int*)d_in[3];
    const float* Wq   = (const float*)d_in[4];  const float* bq   = (const float*)d_in[5];
    const float* Wk   = (const float*)d_in[6];  const float* bk   = (const float*)d_in[7];
    const float* Wv   = (const float*)d_in[8];  const float* bv   = (const float*)d_in[9];
    const float* We   = (const float*)d_in[10]; const float* be   = (const float*)d_in[11];
    const float* Wev  = (const float*)d_in[12]; const float* bev  = (const float*)d_in[13];
    const float* Wout = (const float*)d_in[14]; const float* bout = (const float*)d_in[15];
    const float* ln_ng = (const float*)d_in[16]; const float* ln_nb = (const float*)d_in[17];
    const float* ln_eg = (const float*)d_in[18]; const float* ln_eb = (const float*)d_in[19];

    float* xout = (float*)d_out;              // [N*128]
    float* yout = xout + (size_t)NN * FDIM;   // [E*128]

    char* ws = (char*)d_ws;
    short* qbf  = (short*)ws;   ws += (size_t)NN * FDIM * 2;
    short* kbf  = (short*)ws;   ws += (size_t)NN * FDIM * 2;
    short* vbf  = (short*)ws;   ws += (size_t)NN * FDIM * 2;
    short* attn = (short*)ws;   ws += (size_t)NE * FDIM * 2;
    short* w16  = (short*)ws;   ws += (size_t)6 * 16384 * 2;
    int*   hist = (int*)ws;     ws += (size_t)NN * 4;
    int*   rows = (int*)ws;     ws += (size_t)NN * 4;
    int*   curs = (int*)ws;     ws += (size_t)NN * 4;
    int*   sidx = (int*)ws;     ws += (size_t)NE * 4;
    int*   bsum = (int*)ws;     ws += (size_t)NB * 4;
    short* wq16  = w16;
    short* wk16  = w16 + 16384;
    short* wv16  = w16 + 32768;
    short* we16  = w16 + 49152;
    short* wev16 = w16 + 65536;
    short* wo16  = w16 + 81920;

    hipMemsetAsync(hist, 0, (size_t)NN * sizeof(int), stream);
    convert_weights<<<384, 256, 0, stream>>>(Wq, Wk, Wv, We, Wev, Wout, w16);
    hist_kernel<<<(NE + 255) / 256, 256, 0, stream>>>(dst, hist);
    scanA_kernel<<<NB, 256, 0, stream>>>(hist, rows, bsum);
    scanB_kernel<<<1, 256, 0, stream>>>(bsum);
    scanC_kernel<<<NB, 256, 0, stream>>>(rows, bsum, curs);
    scatter_kernel<<<(NE + 255) / 256, 256, 0, stream>>>(dst, curs, sidx);
    node_proj_kernel<<<(NN + 63) / 64, 256, 0, stream>>>(
        nf, wq16, wk16, wv16, wo16, bq, bk, bv, bout, qbf, kbf, vbf, xout);
    edge_m_kernel<<<NE / 64, 256, 0, stream>>>(
        ef, src, dst, we16, wev16, be, bev, qbf, kbf, ln_eg, ln_eb, attn, yout);
    node_agg_kernel<<<(NN + 3) / 4, 256, 0, stream>>>(
        rows, hist, sidx, src, attn, vbf, ln_ng, ln_nb, xout);
}